// Round 3
// baseline (428.254 us; speedup 1.0000x reference)
//
#include <hip/hip_runtime.h>
#include <stdint.h>

#define DEV __device__ __forceinline__

typedef __attribute__((ext_vector_type(8))) short bf16x8;
typedef __attribute__((ext_vector_type(4))) float f32x4;
typedef __attribute__((ext_vector_type(8))) unsigned short u16x8;
typedef __attribute__((ext_vector_type(4))) unsigned short u16x4;

DEV unsigned short f2bf(float f) {
  union { float f; unsigned int u; } v; v.f = f;
  unsigned int u = v.u;
  return (unsigned short)((u + 0x7FFFu + ((u >> 16) & 1u)) >> 16);
}
DEV float bf2f(unsigned short u) {
  union { unsigned int u; float f; } v; v.u = ((unsigned int)u) << 16;
  return v.f;
}
DEV f32x4 mfma16(bf16x8 a, bf16x8 b, f32x4 c) {
  return __builtin_amdgcn_mfma_f32_16x16x32_bf16(a, b, c, 0, 0, 0);
}
DEV void gl_lds16(const void* g, void* l) {
  __builtin_amdgcn_global_load_lds(
      (const __attribute__((address_space(1))) void*)g,
      (__attribute__((address_space(3))) void*)l, 16, 0, 0);
}

// ---------------- convert x (fp32 -> bf16) ----------------
__global__ __launch_bounds__(256) void k_cvt_bf16(const float* __restrict__ in,
                                                  unsigned short* __restrict__ out,
                                                  int n8) {
  int i = blockIdx.x * 256 + threadIdx.x;
  if (i >= n8) return;
  const float4* p = (const float4*)in + (size_t)i * 2;
  float4 a = p[0], b = p[1];
  u16x8 o;
  o[0] = f2bf(a.x); o[1] = f2bf(a.y); o[2] = f2bf(a.z); o[3] = f2bf(a.w);
  o[4] = f2bf(b.x); o[5] = f2bf(b.y); o[6] = f2bf(b.z); o[7] = f2bf(b.w);
  ((u16x8*)out)[i] = o;
}

// ---------------- GK[h][s][dd] = sum_d Wk[dd][d] * G[h,s,d] ----------------
__global__ void k_gk(const float* __restrict__ Wk, const float* __restrict__ qg,
                     float* __restrict__ GK) {
  int idx = blockIdx.x * 256 + threadIdx.x;  // 32768
  int dd = idx & 63, s = (idx >> 6) & 63, h = idx >> 12;
  float a = 0.f;
#pragma unroll 8
  for (int d = 0; d < 64; ++d) a += Wk[dd * 64 + d] * qg[((size_t)(h * 64 + s)) * 64 + d];
  GK[idx] = a;
}

// ---------------- Wcat rows 0..511: Wl^T[hs][c] = sum_dd Wx[c][h*64+dd]*GK[h,s,dd] ----
__global__ void k_wl(const float* __restrict__ Wx, const float* __restrict__ GK,
                     unsigned short* __restrict__ Wcat) {
  int idx = blockIdx.x * 256 + threadIdx.x;  // 262144
  int c = idx & 511, hs = idx >> 9;
  int h = hs >> 6;
  float a = 0.f;
#pragma unroll 8
  for (int dd = 0; dd < 64; ++dd) a += Wx[(size_t)c * 512 + h * 64 + dd] * GK[hs * 64 + dd];
  Wcat[(size_t)hs * 512 + c] = f2bf(a);
}

// ---------------- Wcat rows 512..1023: Wv^T fused ----------------
__global__ void k_wv(const float* __restrict__ Wx, const float* __restrict__ Wv,
                     unsigned short* __restrict__ Wcat) {
  int idx = blockIdx.x * 256 + threadIdx.x;  // 262144
  int c = idx & 511, o = idx >> 9;
  int h = o >> 6, dp = o & 63;
  float a = 0.f;
#pragma unroll 8
  for (int dd = 0; dd < 64; ++dd) a += Wx[(size_t)c * 512 + h * 64 + dd] * Wv[dd * 64 + dp];
  Wcat[(size_t)(512 + o) * 512 + c] = f2bf(a);
}

// ---------------- fused biases: [0..511]=bl (logit bias), [512..1023]=bfv ----------------
__global__ void k_bias(const float* __restrict__ bx, const float* __restrict__ bk,
                       const float* __restrict__ bv, const float* __restrict__ Wk,
                       const float* __restrict__ Wv, const float* __restrict__ qg,
                       float* __restrict__ bias) {
  int o = blockIdx.x * 256 + threadIdx.x;  // 1024
  if (o >= 1024) return;
  if (o < 512) {
    int h = o >> 6, s = o & 63;
    float a = 0.f;
    for (int dp = 0; dp < 64; ++dp) {
      float bkf = bk[dp];
      for (int dd = 0; dd < 64; ++dd) bkf += bx[h * 64 + dd] * Wk[dd * 64 + dp];
      a += bkf * qg[((size_t)(h * 64 + s)) * 64 + dp];
    }
    bias[o] = a;
  } else {
    int o2 = o - 512, h = o2 >> 6, dp = o2 & 63;
    float a = bv[dp];
    for (int dd = 0; dd < 64; ++dd) a += bx[h * 64 + dd] * Wv[dd * 64 + dp];
    bias[o] = a;
  }
}

__global__ void k_wo_t(const float* __restrict__ Wo, unsigned short* __restrict__ WoT) {
  int idx = blockIdx.x * 256 + threadIdx.x;  // 262144
  int i = idx >> 9, o = idx & 511;
  WoT[(size_t)o * 512 + i] = f2bf(Wo[(size_t)i * 512 + o]);
}

// ---------------- GEMM1: [L | v] = x @ Wcat^T + bias ----------------
// 128x128 tile, BK=32 double-buffer (32 KB LDS -> high occupancy + prefetch),
// XCD-chunked grid. L cols -> bf16 row-major; v cols -> vT[bh][d][n] transposed.
__global__ __launch_bounds__(256) void k_gemm1(const unsigned short* __restrict__ A,
                                               const unsigned short* __restrict__ BT,
                                               const float* __restrict__ bias,
                                               unsigned short* __restrict__ Lout,
                                               unsigned short* __restrict__ vT, int NT) {
  __shared__ unsigned short As[2][4096];
  __shared__ unsigned short Bs[2][4096];
  const int tid = threadIdx.x;
  const int w = tid >> 6, lane = tid & 63;
  const int l = lane & 15, g = lane >> 4;
  unsigned bid = blockIdx.x;
  unsigned perx = gridDim.x >> 3;
  unsigned nbid = (bid & 7) * perx + (bid >> 3);
  const int ntile = nbid % NT, mtile = nbid / NT;
  const int bm = mtile * 128, bn = ntile * 128;
  const int wm = (w >> 1) * 64, wn = (w & 1) * 64;
  const int lr = lane >> 2;        // 0..15 row within 1KB chunk
  const int lc = (lane & 3) * 8;   // k elem offset (16B)
  f32x4 acc[4][4] = {};

#define STG(buf, k0)                                                          \
  {                                                                           \
    _Pragma("unroll") for (int i = 0; i < 2; ++i) {                           \
      int q = w * 2 + i;                                                      \
      int row = q * 16 + lr;                                                  \
      gl_lds16(A + (size_t)(bm + row) * 512 + (k0) + lc, &As[buf][q * 512]);  \
      gl_lds16(BT + (size_t)(bn + row) * 512 + (k0) + lc, &Bs[buf][q * 512]); \
    }                                                                         \
  }

  STG(0, 0);
  __syncthreads();
  int cur = 0;
#pragma unroll 2
  for (int t = 0; t < 16; ++t) {
    if (t < 15) STG(cur ^ 1, (t + 1) * 32);
    bf16x8 af[4], bfr[4];
#pragma unroll
    for (int fm = 0; fm < 4; ++fm)
      af[fm] = *(const bf16x8*)&As[cur][(wm + fm * 16 + l) * 32 + g * 8];
#pragma unroll
    for (int fn = 0; fn < 4; ++fn)
      bfr[fn] = *(const bf16x8*)&Bs[cur][(wn + fn * 16 + l) * 32 + g * 8];
#pragma unroll
    for (int fm = 0; fm < 4; ++fm)
#pragma unroll
      for (int fn = 0; fn < 4; ++fn)
        acc[fm][fn] = mfma16(af[fm], bfr[fn], acc[fm][fn]);
    __syncthreads();
    cur ^= 1;
  }
#undef STG

#pragma unroll
  for (int fm = 0; fm < 4; ++fm)
#pragma unroll
    for (int fn = 0; fn < 4; ++fn) {
      int colg = bn + wn + fn * 16 + l;
      float bcol = bias[colg];
      int row0 = bm + wm + fm * 16 + g * 4;
      if (colg < 512) {  // L half, row-major bf16
#pragma unroll
        for (int r = 0; r < 4; ++r)
          Lout[(size_t)(row0 + r) * 512 + colg] = f2bf(acc[fm][fn][r] + bcol);
      } else {  // v half -> vT[(b*8+h)*64+d][n]
        int c2 = colg - 512, h = c2 >> 6, d = c2 & 63;
        int b = row0 >> 14, nn = row0 & 16383;
        u16x4 o;
#pragma unroll
        for (int r = 0; r < 4; ++r) o[r] = f2bf(acc[fm][fn][r] + bcol);
        *(u16x4*)&vT[(((size_t)(b * 8 + h)) * 64 + d) * 16384 + nn] = o;
      }
    }
}

// ---------------- pass 1: flash over n, A=exp(L) direct from LDS-transposed tiles ----
__global__ __launch_bounds__(256) void k_pass1(const unsigned short* __restrict__ L,
                                               const unsigned short* __restrict__ vT,
                                               float* __restrict__ zpart,
                                               float* __restrict__ mpart,
                                               float* __restrict__ dpart) {
  __shared__ unsigned short Ls[64 * 128];  // [s][n], XOR-swizzled, 16 KB
  int chunk = blockIdx.x, bh = blockIdx.y;
  int b = bh >> 3, h = bh & 7;
  int tid = threadIdx.x, w = tid >> 6, lane = tid & 63, l = lane & 15, g = lane >> 4;
  const int sn = tid & 127, sg = tid >> 7;  // staging: column n, s-half
  f32x4 zacc[4] = {};
  float m_run = -1e30f, d_run = 0.f;
  const int s = w * 16 + l;  // this lane's P-row
  for (int t = 0; t < 8; ++t) {
    int n0 = chunk * 1024 + t * 128;
    if (t) __syncthreads();  // prior tile's reads complete before overwrite
#pragma unroll
    for (int j = 0; j < 4; ++j) {  // transpose-stage L[n][h*64+s] -> Ls[s][n]
      int s0 = sg * 32 + j * 8;
      u16x8 vl = *(const u16x8*)&L[((size_t)(b * 16384 + n0 + sn)) * 512 + h * 64 + s0];
#pragma unroll
      for (int e = 0; e < 8; ++e) {
        int ss = s0 + e;
        Ls[(ss * 256 + ((sn * 2) ^ ((ss & 7) << 4))) >> 1] = vl[e];
      }
    }
    __syncthreads();
    // load A-frags (this lane: row s, n-chunks), softmax online
    bf16x8 aL[4];
#pragma unroll
    for (int kc = 0; kc < 4; ++kc)
      aL[kc] = *(const bf16x8*)&Ls[(s * 256 + ((kc * 64 + g * 16) ^ ((s & 7) << 4))) >> 1];
    float fv[32];
#pragma unroll
    for (int kc = 0; kc < 4; ++kc)
#pragma unroll
      for (int e = 0; e < 8; ++e) fv[kc * 8 + e] = bf2f((unsigned short)aL[kc][e]);
    float tmax = -1e30f;
#pragma unroll
    for (int i = 0; i < 32; ++i) tmax = fmaxf(tmax, fv[i]);
    tmax = fmaxf(tmax, __shfl_xor(tmax, 16));
    tmax = fmaxf(tmax, __shfl_xor(tmax, 32));
    float newm = fmaxf(m_run, tmax);
    float scale = __expf(m_run - newm);
    float psum = 0.f;
    bf16x8 pf[4];
#pragma unroll
    for (int kc = 0; kc < 4; ++kc)
#pragma unroll
      for (int e = 0; e < 8; ++e) {
        float p = __expf(fv[kc * 8 + e] - newm);
        psum += p;
        pf[kc][e] = (short)f2bf(p);
      }
    psum += __shfl_xor(psum, 16);
    psum += __shfl_xor(psum, 32);
    d_run = d_run * scale + psum;
    m_run = newm;
    float sc[4];
#pragma unroll
    for (int r = 0; r < 4; ++r) sc[r] = __shfl(scale, g * 4 + r);
#pragma unroll
    for (int fd = 0; fd < 4; ++fd)
#pragma unroll
      for (int r = 0; r < 4; ++r) zacc[fd][r] *= sc[r];
    // z += P @ v ; B-frags direct from global vT (L1/L2-hot tile)
#pragma unroll
    for (int kc = 0; kc < 4; ++kc) {
#pragma unroll
      for (int fd = 0; fd < 4; ++fd) {
        bf16x8 bv = *(const bf16x8*)&vT[((size_t)(bh * 64 + fd * 16 + l)) * 16384 + n0 +
                                        kc * 32 + g * 8];
        zacc[fd] = mfma16(pf[kc], bv, zacc[fd]);
      }
    }
  }
  size_t base = ((size_t)bh * 16 + chunk) * 64;
#pragma unroll
  for (int fd = 0; fd < 4; ++fd)
#pragma unroll
    for (int r = 0; r < 4; ++r) {
      int so = w * 16 + g * 4 + r, d = fd * 16 + l;
      zpart[(base + so) * 64 + d] = zacc[fd][r];
    }
  if (g == 0) {
    mpart[base + w * 16 + l] = m_run;
    dpart[base + w * 16 + l] = d_run;
  }
}

// ---------------- reduce partials -> z fp32 [bh][s][d] ----------------
__global__ void k_zred(const float* __restrict__ zpart, const float* __restrict__ mpart,
                       const float* __restrict__ dpart, float* __restrict__ z) {
  int bh = blockIdx.x, tid = threadIdx.x;
  for (int i = 0; i < 16; ++i) {
    int idx = i * 256 + tid;  // 0..4095
    int s = idx >> 6, d = idx & 63;
    float mg = -1e30f;
    for (int c = 0; c < 16; ++c) mg = fmaxf(mg, mpart[((size_t)bh * 16 + c) * 64 + s]);
    float den = 0.f, num = 0.f;
    for (int c = 0; c < 16; ++c) {
      float e = __expf(mpart[((size_t)bh * 16 + c) * 64 + s] - mg);
      den += e * dpart[((size_t)bh * 16 + c) * 64 + s];
      num += e * zpart[(((size_t)bh * 16 + c) * 64 + s) * 64 + d];
    }
    z[(size_t)bh * 4096 + idx] = num / den;
  }
}

// ---------------- zWoT[b][c][hs] = sum_d z[b,h,s,d] * WoT[c][h*64+d] ----------------
__global__ void k_zwo(const float* __restrict__ z, const unsigned short* __restrict__ WoT,
                      unsigned short* __restrict__ zWoT) {
  int idx = blockIdx.x * 256 + threadIdx.x;  // 1048576
  int hs = idx & 511, c = (idx >> 9) & 511, b = idx >> 18;
  int h = hs >> 6, s = hs & 63;
  const float* zp = z + ((size_t)(b * 8 + h) * 64 + s) * 64;
  const unsigned short* wp = WoT + (size_t)c * 512 + h * 64;
  float a = 0.f;
#pragma unroll 8
  for (int d = 0; d < 64; ++d) a += zp[d] * bf2f(wp[d]);
  zWoT[((size_t)(b * 512) + c) * 512 + hs] = f2bf(a);
}

// ---------------- GEMM2: out = softmax_h(L) @ zWoT_b + bo ----------------
// 64-token tile; softmax into LDS (padded 520); K=512 fully resident -> barrier-free
// MFMA loop; B direct-global (L2-hot 512KB/b); fn split in 2 passes to cap VGPR.
__global__ __launch_bounds__(256) void k_gemm2(const unsigned short* __restrict__ L,
                                               const unsigned short* __restrict__ zWoT,
                                               const float* __restrict__ bo,
                                               float* __restrict__ out) {
  __shared__ unsigned short P2s[64 * 520];
  int row0 = blockIdx.x * 64;
  int b = row0 >> 14;
  int tid = threadIdx.x, w = tid >> 6, lane = tid & 63, l = lane & 15, g = lane >> 4;
  {  // softmax phase: 4 threads per token row, 2 head-groups each
    int row = tid >> 2, q = tid & 3;
    const unsigned short* lp = L + (size_t)(row0 + row) * 512;
#pragma unroll
    for (int hh = 0; hh < 2; ++hh) {
      int h = q * 2 + hh;
      float f[64];
#pragma unroll
      for (int j = 0; j < 8; ++j) {
        u16x8 rv = *(const u16x8*)&lp[h * 64 + j * 8];
#pragma unroll
        for (int e = 0; e < 8; ++e) f[j * 8 + e] = bf2f(rv[e]);
      }
      float mx = -1e30f;
#pragma unroll
      for (int i = 0; i < 64; ++i) mx = fmaxf(mx, f[i]);
      float sm = 0.f;
#pragma unroll
      for (int i = 0; i < 64; ++i) {
        float p = __expf(f[i] - mx);
        f[i] = p;
        sm += p;
      }
      float inv = 1.f / sm;
#pragma unroll
      for (int j = 0; j < 8; ++j) {
        u16x8 o;
#pragma unroll
        for (int e = 0; e < 8; ++e) o[e] = f2bf(f[j * 8 + e] * inv);
        *(u16x8*)((char*)P2s + (row * 1040 + h * 128 + j * 16)) = o;
      }
    }
  }
  __syncthreads();
#pragma unroll
  for (int p = 0; p < 2; ++p) {
    f32x4 acc[4][4] = {};
#pragma unroll 4
    for (int kc = 0; kc < 16; ++kc) {
      bf16x8 aA[4], bB[4];
#pragma unroll
      for (int fm = 0; fm < 4; ++fm)
        aA[fm] = *(const bf16x8*)((const char*)P2s + ((fm * 16 + l) * 1040 + kc * 64 + g * 16));
#pragma unroll
      for (int fn = 0; fn < 4; ++fn) {
        int col = w * 128 + p * 64 + fn * 16 + l;
        bB[fn] = *(const bf16x8*)&zWoT[((size_t)(b * 512) + col) * 512 + kc * 32 + g * 8];
      }
#pragma unroll
      for (int fm = 0; fm < 4; ++fm)
#pragma unroll
        for (int fn = 0; fn < 4; ++fn) acc[fm][fn] = mfma16(aA[fm], bB[fn], acc[fm][fn]);
    }
#pragma unroll
    for (int fm = 0; fm < 4; ++fm)
#pragma unroll
      for (int fn = 0; fn < 4; ++fn) {
        int col = w * 128 + p * 64 + fn * 16 + l;
        float bb = bo[col];
#pragma unroll
        for (int r = 0; r < 4; ++r)
          out[(size_t)(row0 + fm * 16 + g * 4 + r) * 512 + col] = acc[fm][fn][r] + bb;
      }
  }
}

extern "C" void kernel_launch(void* const* d_in, const int* in_sizes, int n_in,
                              void* d_out, int out_size, void* d_ws, size_t ws_size,
                              hipStream_t stream) {
  const float* x  = (const float*)d_in[0];
  const float* qg = (const float*)d_in[1];
  const float* Wx = (const float*)d_in[2];
  const float* bx = (const float*)d_in[3];
  const float* Wk = (const float*)d_in[4];
  const float* bk = (const float*)d_in[5];
  const float* Wv = (const float*)d_in[6];
  const float* bv = (const float*)d_in[7];
  const float* Wo = (const float*)d_in[8];
  const float* bo = (const float*)d_in[9];
  float* out = (float*)d_out;

  char* ws = (char*)d_ws;
  unsigned short* xbf  = (unsigned short*)(ws);               // 64 MiB
  unsigned short* Lbuf = (unsigned short*)(ws + 67108864);    // 64 MiB
  unsigned short* Wcat = (unsigned short*)(ws + 134217728);   // 1 MiB
  unsigned short* WoT  = (unsigned short*)(ws + 135266304);   // 0.5 MiB
  float* bias          = (float*)(ws + 135790592);            // 4 KiB
  float* GK            = (float*)(ws + 135794688);            // 128 KiB
  unsigned short* zWoT = (unsigned short*)(ws + 135925760);   // 2 MiB (live during GEMM2)
  // dead-before-GEMM2 scratch lives in d_out:
  char* dout = (char*)d_out;
  unsigned short* vT = (unsigned short*)(dout);               // 64 MiB
  float* zpart       = (float*)(dout + 67108864);             // 8 MiB
  float* mpart       = (float*)(dout + 75497472);             // 128 KiB
  float* dpart       = (float*)(dout + 75628544);             // 128 KiB
  float* zbuf        = (float*)(dout + 75759616);             // 512 KiB

  k_cvt_bf16<<<dim3(16384), dim3(256), 0, stream>>>(x, xbf, 4194304);
  k_gk<<<dim3(128), dim3(256), 0, stream>>>(Wk, qg, GK);
  k_wl<<<dim3(1024), dim3(256), 0, stream>>>(Wx, GK, Wcat);
  k_wv<<<dim3(1024), dim3(256), 0, stream>>>(Wx, Wv, Wcat);
  k_bias<<<dim3(4), dim3(256), 0, stream>>>(bx, bk, bv, Wk, Wv, qg, bias);
  k_wo_t<<<dim3(1024), dim3(256), 0, stream>>>(Wo, WoT);
  // [L | v] = x @ Wcat^T + bias -> Lbuf [65536][512] bf16, vT [32][64][16384] bf16
  k_gemm1<<<dim3(4096), dim3(256), 0, stream>>>(xbf, Wcat, bias, Lbuf, vT, 8);
  k_pass1<<<dim3(16, 32), dim3(256), 0, stream>>>(Lbuf, vT, zpart, mpart, dpart);
  k_zred<<<dim3(32), dim3(256), 0, stream>>>(zpart, mpart, dpart, zbuf);
  k_zwo<<<dim3(4096), dim3(256), 0, stream>>>(zbuf, WoT, zWoT);
  // out = softmax(L) @ zWoT + bo  (overwrites all d_out scratch)
  k_gemm2<<<dim3(1024), dim3(256), 0, stream>>>(Lbuf, zWoT, bo, out);
}

// Round 4
// 329.723 us; speedup vs baseline: 1.2988x; 1.2988x over previous
//
#include <hip/hip_runtime.h>
#include <stdint.h>

#define DEV __device__ __forceinline__

typedef __attribute__((ext_vector_type(8))) short bf16x8;
typedef __attribute__((ext_vector_type(4))) float f32x4;
typedef __attribute__((ext_vector_type(8))) unsigned short u16x8;
typedef __attribute__((ext_vector_type(4))) unsigned short u16x4;

DEV unsigned short f2bf(float f) {
  union { float f; unsigned int u; } v; v.f = f;
  unsigned int u = v.u;
  return (unsigned short)((u + 0x7FFFu + ((u >> 16) & 1u)) >> 16);
}
DEV float bf2f(unsigned short u) {
  union { unsigned int u; float f; } v; v.u = ((unsigned int)u) << 16;
  return v.f;
}
DEV f32x4 mfma16(bf16x8 a, bf16x8 b, f32x4 c) {
  return __builtin_amdgcn_mfma_f32_16x16x32_bf16(a, b, c, 0, 0, 0);
}
DEV void gl_lds16(const void* g, void* l) {
  __builtin_amdgcn_global_load_lds(
      (const __attribute__((address_space(1))) void*)g,
      (__attribute__((address_space(3))) void*)l, 16, 0, 0);
}

// ---------------- convert x (fp32 -> bf16) ----------------
__global__ __launch_bounds__(256) void k_cvt_bf16(const float* __restrict__ in,
                                                  unsigned short* __restrict__ out,
                                                  int n8) {
  int i = blockIdx.x * 256 + threadIdx.x;
  if (i >= n8) return;
  const float4* p = (const float4*)in + (size_t)i * 2;
  float4 a = p[0], b = p[1];
  u16x8 o;
  o[0] = f2bf(a.x); o[1] = f2bf(a.y); o[2] = f2bf(a.z); o[3] = f2bf(a.w);
  o[4] = f2bf(b.x); o[5] = f2bf(b.y); o[6] = f2bf(b.z); o[7] = f2bf(b.w);
  ((u16x8*)out)[i] = o;
}

// ---------------- GK[h][s][dd] = sum_d Wk[dd][d] * G[h,s,d] ----------------
__global__ void k_gk(const float* __restrict__ Wk, const float* __restrict__ qg,
                     float* __restrict__ GK) {
  int idx = blockIdx.x * 256 + threadIdx.x;  // 32768
  int dd = idx & 63, hs = idx >> 6;
  float a = 0.f;
#pragma unroll 8
  for (int d = 0; d < 64; ++d) a += Wk[dd * 64 + d] * qg[(size_t)hs * 64 + d];
  GK[idx] = a;
}

// ---------------- Wcat rows 0..511: Wl^T[hs][c] = sum_dd Wx[c][h*64+dd]*GK[h,s,dd] ----
__global__ void k_wl(const float* __restrict__ Wx, const float* __restrict__ GK,
                     unsigned short* __restrict__ Wcat) {
  int idx = blockIdx.x * 256 + threadIdx.x;  // 262144
  int c = idx & 511, hs = idx >> 9;
  int h = hs >> 6;
  float a = 0.f;
#pragma unroll 8
  for (int dd = 0; dd < 64; ++dd) a += Wx[(size_t)c * 512 + h * 64 + dd] * GK[hs * 64 + dd];
  Wcat[(size_t)hs * 512 + c] = f2bf(a);
}

// ---------------- Wcat rows 512..1023: Wv^T fused ----------------
__global__ void k_wv(const float* __restrict__ Wx, const float* __restrict__ Wv,
                     unsigned short* __restrict__ Wcat) {
  int idx = blockIdx.x * 256 + threadIdx.x;  // 262144
  int c = idx & 511, o = idx >> 9;
  int h = o >> 6, dp = o & 63;
  float a = 0.f;
#pragma unroll 8
  for (int dd = 0; dd < 64; ++dd) a += Wx[(size_t)c * 512 + h * 64 + dd] * Wv[dd * 64 + dp];
  Wcat[(size_t)(512 + o) * 512 + c] = f2bf(a);
}

// ---------------- fused biases via GK ----------------
__global__ void k_bias2(const float* __restrict__ bx, const float* __restrict__ bk,
                        const float* __restrict__ bv, const float* __restrict__ Wv,
                        const float* __restrict__ qg, const float* __restrict__ GK,
                        float* __restrict__ bias) {
  int o = blockIdx.x * 256 + threadIdx.x;
  if (o >= 1024) return;
  if (o < 512) {
    int h = o >> 6;
    float a = 0.f;
    for (int dd = 0; dd < 64; ++dd) a += bx[h * 64 + dd] * GK[(size_t)o * 64 + dd];
    for (int dp = 0; dp < 64; ++dp) a += bk[dp] * qg[(size_t)o * 64 + dp];
    bias[o] = a;
  } else {
    int o2 = o - 512, h = o2 >> 6, dp = o2 & 63;
    float a = bv[dp];
    for (int dd = 0; dd < 64; ++dd) a += bx[h * 64 + dd] * Wv[dd * 64 + dp];
    bias[o] = a;
  }
}

__global__ void k_wo_t(const float* __restrict__ Wo, unsigned short* __restrict__ WoT) {
  int idx = blockIdx.x * 256 + threadIdx.x;  // 262144
  int i = idx >> 9, o = idx & 511;
  WoT[(size_t)o * 512 + i] = f2bf(Wo[(size_t)i * 512 + o]);
}

// =================== 256x256 counted-vmcnt GEMM template ===================
// 8 waves (2M x 4N), BK=64, K=512 (8 tiles), 128 KiB LDS double-buffer.
// Raw s_barrier + s_waitcnt vmcnt(8) (never 0 mid-loop); stage(t+2) into the
// current buffer only after explicit lgkmcnt(0)+barrier (all waves' reads
// drained -> race-free). LDS XOR-swizzle via pre-swizzled global source.
// MODE 0: out = A@BT_b^T + bias (fp32), BT_b = BTg + (bm>>14)*512*512.
// MODE 1: cols 0..511 -> softmax epilogue (P2 row-major bf16 + LTe[bh][s][n]);
//         cols 512..1023 -> vT[bh][d][n].
template <int MODE>
__global__ __launch_bounds__(512, 2) void k_mm(const unsigned short* __restrict__ A,
                                               const unsigned short* __restrict__ BTg,
                                               const float* __restrict__ bias,
                                               float* __restrict__ outF,
                                               unsigned short* __restrict__ P2,
                                               unsigned short* __restrict__ LTe,
                                               unsigned short* __restrict__ vT, int NT) {
  extern __shared__ char ldsb[];  // 131072 B: [2][A 32KB | B 32KB]
  const int tid = threadIdx.x;
  const int w = tid >> 6, lane = tid & 63, l = lane & 15, g = lane >> 4;
  unsigned bid = blockIdx.x, perx = gridDim.x >> 3;
  unsigned nbid = (bid & 7) * perx + (bid >> 3);
  const int ntile = nbid % NT, mtile = nbid / NT;
  const int bm = mtile * 256, bn = ntile * 256;
  const int wm = (w >> 2) * 128, wn = (w & 3) * 64;
  const int b = bm >> 14;
  const unsigned short* BT = (MODE == 0) ? BTg + ((size_t)b << 18) : BTg;
  f32x4 acc[8][4] = {};

#define STG(buf, t)                                                             \
  {                                                                             \
    const int k0_ = (t) * 64;                                                   \
    _Pragma("unroll") for (int i_ = 0; i_ < 4; ++i_) {                          \
      int off_ = i_ * 8192 + tid * 16;                                          \
      int row_ = off_ >> 7;                                                     \
      int kbs_ = (off_ & 127) ^ ((row_ & 7) << 4);                              \
      gl_lds16(A + (size_t)(bm + row_) * 512 + k0_ + (kbs_ >> 1),               \
               ldsb + (buf) * 65536 + off_);                                    \
      gl_lds16(BT + (size_t)(bn + row_) * 512 + k0_ + (kbs_ >> 1),              \
               ldsb + (buf) * 65536 + 32768 + off_);                            \
    }                                                                           \
  }

  STG(0, 0);
  STG(1, 1);
  const int sx = (l & 7) << 4;
  const int kb0 = (g << 4) ^ sx;
  const int kb1 = (64 | (g << 4)) ^ sx;
  int cur = 0;
#pragma unroll 2
  for (int t = 0; t < 8; ++t) {
    if (t < 7) asm volatile("s_waitcnt vmcnt(8)" ::: "memory");
    else       asm volatile("s_waitcnt vmcnt(0)" ::: "memory");
    __builtin_amdgcn_s_barrier();
    __builtin_amdgcn_sched_barrier(0);
    const char* ab = ldsb + cur * 65536;
    const char* bb = ab + 32768;
    bf16x8 bf[4][2], a1[4][2], a2[4][2];
#pragma unroll
    for (int fn = 0; fn < 4; ++fn) {
      int r = (wn + fn * 16 + l) * 128;
      bf[fn][0] = *(const bf16x8*)(bb + r + kb0);
      bf[fn][1] = *(const bf16x8*)(bb + r + kb1);
    }
#pragma unroll
    for (int fm = 0; fm < 4; ++fm) {
      int r = (wm + fm * 16 + l) * 128;
      a1[fm][0] = *(const bf16x8*)(ab + r + kb0);
      a1[fm][1] = *(const bf16x8*)(ab + r + kb1);
    }
    __builtin_amdgcn_s_setprio(1);
#pragma unroll
    for (int fm = 0; fm < 4; ++fm)
#pragma unroll
      for (int fn = 0; fn < 4; ++fn) {
        acc[fm][fn] = mfma16(a1[fm][0], bf[fn][0], acc[fm][fn]);
        acc[fm][fn] = mfma16(a1[fm][1], bf[fn][1], acc[fm][fn]);
      }
    __builtin_amdgcn_s_setprio(0);
#pragma unroll
    for (int fm = 0; fm < 4; ++fm) {
      int r = (wm + 64 + fm * 16 + l) * 128;
      a2[fm][0] = *(const bf16x8*)(ab + r + kb0);
      a2[fm][1] = *(const bf16x8*)(ab + r + kb1);
    }
    asm volatile("s_waitcnt lgkmcnt(0)" ::: "memory");
    __builtin_amdgcn_sched_barrier(0);
    __builtin_amdgcn_s_barrier();   // all waves' reads of buf[cur] done
    __builtin_amdgcn_sched_barrier(0);
    if (t < 6) STG(cur, t + 2);     // safe overwrite of buf[cur]
    __builtin_amdgcn_s_setprio(1);
#pragma unroll
    for (int fm = 0; fm < 4; ++fm)
#pragma unroll
      for (int fn = 0; fn < 4; ++fn) {
        acc[fm + 4][fn] = mfma16(a2[fm][0], bf[fn][0], acc[fm + 4][fn]);
        acc[fm + 4][fn] = mfma16(a2[fm][1], bf[fn][1], acc[fm + 4][fn]);
      }
    __builtin_amdgcn_s_setprio(0);
    cur ^= 1;
  }
#undef STG

  if (MODE == 0) {
#pragma unroll
    for (int fm = 0; fm < 8; ++fm)
#pragma unroll
      for (int fn = 0; fn < 4; ++fn) {
        int col = bn + wn + fn * 16 + l;
        float bb2 = bias[col];
        int row0 = bm + wm + fm * 16 + g * 4;
#pragma unroll
        for (int r = 0; r < 4; ++r)
          outF[(size_t)(row0 + r) * 512 + col] = acc[fm][fn][r] + bb2;
      }
  } else if (bn < 512) {
    int hglob = (bn >> 6) + (w & 3);
    int nloc0 = (bm & 16383) + wm;
#pragma unroll
    for (int fm = 0; fm < 8; ++fm)
#pragma unroll
      for (int fn = 0; fn < 4; ++fn) {
        float bb2 = bias[bn + wn + fn * 16 + l];
#pragma unroll
        for (int r = 0; r < 4; ++r)
          acc[fm][fn][r] = __expf(acc[fm][fn][r] + bb2 - 8.0f);
      }
#pragma unroll
    for (int fm = 0; fm < 8; ++fm) {
      f32x4 rs;
#pragma unroll
      for (int r = 0; r < 4; ++r)
        rs[r] = (acc[fm][0][r] + acc[fm][1][r]) + (acc[fm][2][r] + acc[fm][3][r]);
#pragma unroll
      for (int m = 1; m < 16; m <<= 1)
#pragma unroll
        for (int r = 0; r < 4; ++r) rs[r] += __shfl_xor(rs[r], m);
      int nglob0 = bm + wm + fm * 16 + g * 4;
#pragma unroll
      for (int r = 0; r < 4; ++r) {
        float rinv = 1.f / rs[r];
#pragma unroll
        for (int fn = 0; fn < 4; ++fn)
          P2[(size_t)(nglob0 + r) * 512 + bn + wn + fn * 16 + l] =
              f2bf(acc[fm][fn][r] * rinv);
      }
#pragma unroll
      for (int fn = 0; fn < 4; ++fn) {
        int s = fn * 16 + l;
        u16x4 o;
#pragma unroll
        for (int r = 0; r < 4; ++r) o[r] = f2bf(acc[fm][fn][r]);
        *(u16x4*)&LTe[((size_t)((b * 8 + hglob) * 64 + s)) * 16384 + nloc0 + fm * 16 + g * 4] = o;
      }
    }
  } else {
    int nloc0 = (bm & 16383) + wm;
#pragma unroll
    for (int fm = 0; fm < 8; ++fm)
#pragma unroll
      for (int fn = 0; fn < 4; ++fn) {
        int c2 = bn - 512 + wn + fn * 16 + l;
        float bb2 = bias[bn + wn + fn * 16 + l];
        int h = c2 >> 6, d = c2 & 63;
        u16x4 o;
#pragma unroll
        for (int r = 0; r < 4; ++r) o[r] = f2bf(acc[fm][fn][r] + bb2);
        *(u16x4*)&vT[(((size_t)(b * 8 + h)) * 64 + d) * 16384 + nloc0 + fm * 16 + g * 4] = o;
      }
  }
}

// ---------------- pass 1: z_part = LTe @ v (pure streaming GEMM) + den ----------------
__global__ __launch_bounds__(256) void k_pass1(const unsigned short* __restrict__ LTe,
                                               const unsigned short* __restrict__ vT,
                                               float* __restrict__ zpart,
                                               float* __restrict__ dpart) {
  int chunk = blockIdx.x, bh = blockIdx.y;
  int tid = threadIdx.x, w = tid >> 6, lane = tid & 63, l = lane & 15, g = lane >> 4;
  const unsigned short* lp = LTe + ((size_t)bh * 64 + w * 16 + l) * 16384 + chunk * 512;
  const unsigned short* vp = vT + (size_t)bh * 64 * 16384 + chunk * 512;
  f32x4 acc[4] = {};
  float dsum = 0.f;
#pragma unroll 4
  for (int ks = 0; ks < 16; ++ks) {
    bf16x8 a = *(const bf16x8*)(lp + ks * 32 + g * 8);
#pragma unroll
    for (int e = 0; e < 8; ++e) dsum += bf2f((unsigned short)a[e]);
#pragma unroll
    for (int fd = 0; fd < 4; ++fd) {
      bf16x8 bv = *(const bf16x8*)(vp + ((size_t)(fd * 16 + l)) * 16384 + ks * 32 + g * 8);
      acc[fd] = mfma16(a, bv, acc[fd]);
    }
  }
  dsum += __shfl_xor(dsum, 16);
  dsum += __shfl_xor(dsum, 32);
  size_t base = ((size_t)bh * 32 + chunk) * 64;
  if (g == 0) dpart[base + w * 16 + l] = dsum;
#pragma unroll
  for (int fd = 0; fd < 4; ++fd)
#pragma unroll
    for (int r = 0; r < 4; ++r)
      zpart[(base + w * 16 + g * 4 + r) * 64 + fd * 16 + l] = acc[fd][r];
}

// ---------------- reduce partials -> z fp32 [bh][s][d] ----------------
__global__ void k_zred(const float* __restrict__ zpart, const float* __restrict__ dpart,
                       float* __restrict__ z) {
  int idx = blockIdx.x * 256 + threadIdx.x;  // 131072
  int bh = idx >> 12, s = (idx >> 6) & 63, d = idx & 63;
  float num = 0.f, den = 0.f;
  for (int c = 0; c < 32; ++c) {
    num += zpart[(((size_t)bh * 32 + c) * 64 + s) * 64 + d];
    den += dpart[((size_t)bh * 32 + c) * 64 + s];
  }
  z[idx] = num / den;
}

// ---------------- zWoT[b][c][hs] = sum_d z[b,h,s,d] * WoT[c][h*64+d] ----------------
__global__ void k_zwo(const float* __restrict__ z, const unsigned short* __restrict__ WoT,
                      unsigned short* __restrict__ zWoT) {
  int idx = blockIdx.x * 256 + threadIdx.x;  // 1048576
  int hs = idx & 511, c = (idx >> 9) & 511, b = idx >> 18;
  int h = hs >> 6;
  const float* zp = z + ((size_t)(b * 8 + h) * 64 + (hs & 63)) * 64;
  const unsigned short* wp = WoT + (size_t)c * 512 + h * 64;
  float a = 0.f;
#pragma unroll 8
  for (int d = 0; d < 64; ++d) a += zp[d] * bf2f(wp[d]);
  zWoT[((size_t)(b * 512) + c) * 512 + hs] = f2bf(a);
}

extern "C" void kernel_launch(void* const* d_in, const int* in_sizes, int n_in,
                              void* d_out, int out_size, void* d_ws, size_t ws_size,
                              hipStream_t stream) {
  const float* x  = (const float*)d_in[0];
  const float* qg = (const float*)d_in[1];
  const float* Wx = (const float*)d_in[2];
  const float* bx = (const float*)d_in[3];
  const float* Wk = (const float*)d_in[4];
  const float* bk = (const float*)d_in[5];
  const float* Wv = (const float*)d_in[6];
  const float* bv = (const float*)d_in[7];
  const float* Wo = (const float*)d_in[8];
  const float* bo = (const float*)d_in[9];
  float* out = (float*)d_out;

  char* ws = (char*)d_ws;
  unsigned short* xbf  = (unsigned short*)(ws);               // 64 MiB (dead after GEMM1)
  float* zpart         = (float*)(ws);                        // 32 MiB, reuses xbf region
  unsigned short* P2   = (unsigned short*)(ws + 67108864);    // 64 MiB
  unsigned short* Wcat = (unsigned short*)(ws + 134217728);   // 1 MiB
  unsigned short* WoT  = (unsigned short*)(ws + 135266304);   // 0.5 MiB
  float* bias          = (float*)(ws + 135790592);            // 4 KiB
  float* GK            = (float*)(ws + 135794688);            // 128 KiB
  unsigned short* zWoT = (unsigned short*)(ws + 135925760);   // 2 MiB
  float* dpart         = (float*)(ws + 138027008);            // 256 KiB
  float* zbuf          = (float*)(ws + 138289152);            // 512 KiB
  // d_out doubles as scratch (dead before final GEMM writes it):
  char* dob = (char*)d_out;
  unsigned short* LTe = (unsigned short*)(dob);               // 64 MiB
  unsigned short* vT  = (unsigned short*)(dob + 67108864);    // 64 MiB

  k_cvt_bf16<<<dim3(16384), dim3(256), 0, stream>>>(x, xbf, 4194304);
  k_gk<<<dim3(128), dim3(256), 0, stream>>>(Wk, qg, GK);
  k_wl<<<dim3(1024), dim3(256), 0, stream>>>(Wx, GK, Wcat);
  k_wv<<<dim3(1024), dim3(256), 0, stream>>>(Wx, Wv, Wcat);
  k_bias2<<<dim3(4), dim3(256), 0, stream>>>(bx, bk, bv, Wv, qg, GK, bias);
  k_wo_t<<<dim3(1024), dim3(256), 0, stream>>>(Wo, WoT);
  // GEMM1: [L|v] = x @ Wcat^T + bias -> P2 (softmaxed) + LTe (exp, transposed) + vT
  k_mm<1><<<dim3(1024), dim3(512), 131072, stream>>>(xbf, Wcat, bias, nullptr, P2, LTe,
                                                     vT, 4);
  k_pass1<<<dim3(32, 32), dim3(256), 0, stream>>>(LTe, vT, zpart, dpart);
  k_zred<<<dim3(512), dim3(256), 0, stream>>>(zpart, dpart, zbuf);
  k_zwo<<<dim3(4096), dim3(256), 0, stream>>>(zbuf, WoT, zWoT);
  // GEMM2: out = P2 @ zWoT_b + bo (overwrites LTe/vT scratch in d_out)
  k_mm<0><<<dim3(512), dim3(512), 131072, stream>>>(P2, zWoT, bo, out, nullptr, nullptr,
                                                    nullptr, 2);
}